// Round 9
// baseline (77.857 us; speedup 1.0000x reference)
//
#include <hip/hip_runtime.h>

#define NB 128
#define NTOK 201
#define EW 204   // u-slot of the att-col-0 (e-column) weight

// Publish LDS writes across a barrier WITHOUT draining vmcnt.
__device__ __forceinline__ void lds_barrier() {
    asm volatile("s_waitcnt lgkmcnt(0)" ::: "memory");
    __builtin_amdgcn_s_barrier();
}

// shared argmax over rv/rix prepared per-thread; writes out[slot], out[640+slot]=base+argmax
__device__ __forceinline__ void argmax_write(
    float* rv, int* rix, float v, int idx, float* __restrict__ out, int slot, int base)
{
    const int tid = threadIdx.x;
    rv[tid] = v; rix[tid] = idx;
    __syncthreads();
    for (int s = 128; s > 0; s >>= 1) {
        if (tid < s) {
            const float v2 = rv[tid + s]; const int i2 = rix[tid + s];
            if (v2 > rv[tid] || (v2 == rv[tid] && i2 < rix[tid])) {
                rv[tid] = v2; rix[tid] = i2;
            }
        }
        __syncthreads();
    }
    if (tid == 0) {
        out[slot]       = rv[0];
        out[640 + slot] = (float)(base + rix[0]);
    }
    __syncthreads();
}

// ---- merged e0+e1 chain (lo=5, M=197). 4 row-classes (w = wave) x 50 float4 col-groups.
// Padded col space p = xcol - 2, valid window p in [3,199); weights float2 (chain0, chain1).
// Rows: xr = 4+w+4k (slot = xr-2; slot-2 and clamped slots are zero-weight), heads row 0 -> wave0
// (chain0), row 1 -> wave1 (chain1) — same mod-4 alignment class as the wave's window rows.
__device__ __forceinline__ void chain_heavy(
    const float* __restrict__ xb, float* __restrict__ out, const int b,
    float2* u01, float (*part0)[212], float (*part1)[212], float* rv, int* rix)
{
    const int tid = threadIdx.x;
    const int g   = tid & 63;
    const int w   = tid >> 6;            // row class: xr === w (mod 4)
    const size_t plane = (size_t)NTOK * NTOK;

    {   // init u from layer-11 rows 0 and 1
        const float* r0 = xb + (size_t)(11 * NB) * plane;
        const float* r1 = r0 + NTOK;
        if (tid < 212) {
            float2 v = make_float2(0.f, 0.f);
            if (tid >= 3 && tid < 199) { v.x = r0[tid + 2]; v.y = r1[tid + 2]; }
            if (tid == EW)             { v.x = r0[0];       v.y = r1[1]; }
            u01[tid] = v;
        }
    }
    __syncthreads();

    const int t_w = (8 - ((b + w + 2) & 3)) & 3;   // (b + w + C) === 0 mod 4
    const int C   = 2 + t_w;                        // 16B-aligned start col

    const float* A = xb + (size_t)(10 * NB) * plane;
    for (int l = 10; l >= 0; --l) {
        if (g < 50) {
            float4 acc0 = make_float4(0.f,0.f,0.f,0.f);
            float4 acc1 = make_float4(0.f,0.f,0.f,0.f);
            if (w < 2) {                 // head rows 0 (chain0) / 1 (chain1)
                const float2 ew = u01[EW];
                const float hw = (w == 0) ? ew.x : ew.y;
                const float4 h = *(const float4*)(A + (size_t)w * NTOK + C + 4 * g);
                if (w == 0) {
                    acc0.x = hw*h.x; acc0.y = hw*h.y; acc0.z = hw*h.z; acc0.w = hw*h.w;
                } else {
                    acc1.x = hw*h.x; acc1.y = hw*h.y; acc1.z = hw*h.z; acc1.w = hw*h.w;
                }
            }
            const float* rp = A + (size_t)(4 + w) * NTOK + C + 4 * g;
            #pragma unroll
            for (int k = 0; k < 49; ++k) {
                const float2 wt = u01[2 + w + 4 * k];
                const float4 a  = *(const float4*)(rp + (size_t)(4 * NTOK) * k);
                acc0.x += wt.x*a.x; acc0.y += wt.x*a.y; acc0.z += wt.x*a.z; acc0.w += wt.x*a.w;
                acc1.x += wt.y*a.x; acc1.y += wt.y*a.y; acc1.z += wt.y*a.z; acc1.w += wt.y*a.w;
            }
            {   // k=49: xr = 200+w; clamp in-class for w>=1, weight slot is zero there
                const float2 wt = u01[2 + w + 196];
                const float4 a  = *(const float4*)(rp + (size_t)(4 * NTOK) * 49
                                                   - (w ? (size_t)(4 * NTOK) : 0));
                acc0.x += wt.x*a.x; acc0.y += wt.x*a.y; acc0.z += wt.x*a.z; acc0.w += wt.x*a.w;
                acc1.x += wt.y*a.x; acc1.y += wt.y*a.y; acc1.z += wt.y*a.z; acc1.w += wt.y*a.w;
            }
            *(float4*)&part0[w][4 * g] = acc0;
            *(float4*)&part1[w][4 * g] = acc1;
        } else if (g == 50 || g == 51) { // e-columns: x col 0 (chain0), col 1 (chain1)
            const int ch = g - 50;
            float s = 0.f;
            if (w == ch) {               // head term A[ch][ch]
                const float2 ew = u01[EW];
                s = (ch == 0 ? ew.x : ew.y) * A[(size_t)ch * NTOK + ch];
            }
            const float* ep = A + (size_t)(4 + w) * NTOK + ch;
            #pragma unroll
            for (int k = 0; k < 49; ++k) {
                const float2 wt = u01[2 + w + 4 * k];
                s += (ch == 0 ? wt.x : wt.y) * ep[(size_t)(4 * NTOK) * k];
            }
            {
                const float2 wt = u01[2 + w + 196];
                s += (ch == 0 ? wt.x : wt.y) * ep[(size_t)(4 * NTOK) * 49
                                                 - (w ? (size_t)(4 * NTOK) : 0)];
            }
            if (ch == 0) part0[w][EW] = s; else part1[w][EW] = s;
        }
        lds_barrier();                   // publish part
        if (tid >= 3 && tid < 199) {     // reduce 4 classes -> new u (shift-undo per class)
            float s0 = 0.f, s1 = 0.f;
            #pragma unroll
            for (int q = 0; q < 4; ++q) {
                const int sh = (8 - ((b + q + 2) & 3)) & 3;
                s0 += part0[q][tid - sh];
                s1 += part1[q][tid - sh];
            }
            u01[tid] = make_float2(s0, s1);
        } else if (tid == EW) {
            float s0 = 0.f, s1 = 0.f;
            #pragma unroll
            for (int q = 0; q < 4; ++q) { s0 += part0[q][EW]; s1 += part1[q][EW]; }
            u01[EW] = make_float2(s0, s1);
        }
        lds_barrier();                   // publish u / guard part reuse
        A -= (size_t)NB * plane;
    }

    // argmax per chain over p in [3,199); ref idx = 2 + p  (= lo-3+p, lo=5)
    for (int ch = 0; ch < 2; ++ch) {
        float v = -INFINITY; int idx = 0x7fffffff;
        if (tid >= 3 && tid < 199) { v = ch ? u01[tid].y : u01[tid].x; idx = tid; }
        argmax_write(rv, rix, v, idx, out, ch * NB + b, 2);
    }
}

// ---- single light chain (M=99). 8 row-classes (rc) x 32 lanes (26 active float4 groups).
// p = xcol-(lo-3), valid [3,101); rows xr = lo-1+rc+8k, slot = 2+rc+8k; head row e done by
// the mod-4-aligned class rc_h = (e-lo+1)&3.
__device__ __forceinline__ void chain_light(
    const float* __restrict__ xb, float* __restrict__ out,
    const int e, const int b, const int lo,
    float* u, float (*part)[212], float* rv, int* rix)
{
    const int tid = threadIdx.x;
    const int g   = tid & 31;
    const int rc  = tid >> 5;            // row class 0..7 (alignment by rc & 3)
    const size_t plane = (size_t)NTOK * NTOK;

    const float* L11 = xb + (size_t)(11 * NB) * plane + (size_t)e * NTOK;
    if (tid < 212) {
        float v = 0.f;
        if (tid >= 3 && tid < 101) v = L11[lo - 3 + tid];
        if (tid == EW)             v = L11[e];
        u[tid] = v;
    }
    __syncthreads();

    const int t_rc = (8 - ((b + 2 * lo - 4 + rc) & 3)) & 3;
    const int C    = (lo - 3) + t_rc;    // 16B-aligned start col for this class
    const int rc_h = (e - lo + 1) & 3;   // head-aligned class

    const float* A = xb + (size_t)(10 * NB) * plane;
    for (int l = 10; l >= 0; --l) {
        if (g < 26) {
            float4 acc = make_float4(0.f,0.f,0.f,0.f);
            if (rc == rc_h) {            // head: x row e (aligned in this class)
                const float hw = u[EW];
                const float4 h = *(const float4*)(A + (size_t)e * NTOK + C + 4 * g);
                acc.x = hw*h.x; acc.y = hw*h.y; acc.z = hw*h.z; acc.w = hw*h.w;
            }
            const float* rp = A + (size_t)(lo - 1 + rc) * NTOK + C + 4 * g;
            #pragma unroll
            for (int k = 0; k < 12; ++k) {
                const float wt = u[2 + rc + 8 * k];
                const float4 a = *(const float4*)(rp + (size_t)(8 * NTOK) * k);
                acc.x += wt*a.x; acc.y += wt*a.y; acc.z += wt*a.z; acc.w += wt*a.w;
            }
            {   // k=12: slot = 98+rc; clamp classes rc>=3 (slot>100 is zero-weight)
                const float wt = u[98 + rc];
                const float4 a = *(const float4*)(rp + (size_t)(8 * NTOK) * 12
                                                  - ((rc >= 3) ? (size_t)(8 * NTOK) : 0));
                acc.x += wt*a.x; acc.y += wt*a.y; acc.z += wt*a.z; acc.w += wt*a.w;
            }
            *(float4*)&part[rc][4 * g] = acc;
        } else if (g == 26) {            // e-column
            float s = 0.f;
            if (rc == 0) s = u[EW] * A[(size_t)e * NTOK + e];
            const float* ep = A + (size_t)(lo - 1 + rc) * NTOK + e;
            #pragma unroll
            for (int k = 0; k < 12; ++k) s += u[2 + rc + 8 * k] * ep[(size_t)(8 * NTOK) * k];
            s += u[98 + rc] * ep[(size_t)(8 * NTOK) * 12 - ((rc >= 3) ? (size_t)(8 * NTOK) : 0)];
            part[rc][EW] = s;
        }
        lds_barrier();
        if (tid >= 3 && tid < 101) {
            float s = 0.f;
            #pragma unroll
            for (int q = 0; q < 8; ++q) {
                const int sh = (8 - ((b + 2 * lo - 4 + q) & 3)) & 3;
                s += part[q][tid - sh];
            }
            u[tid] = s;
        } else if (tid == EW) {
            float s = 0.f;
            #pragma unroll
            for (int q = 0; q < 8; ++q) s += part[q][EW];
            u[EW] = s;
        }
        lds_barrier();
        A -= (size_t)NB * plane;
    }

    float v = -INFINITY; int idx = 0x7fffffff;
    if (tid >= 3 && tid < 101) { v = u[tid]; idx = tid; }
    argmax_write(rv, rix, v, idx, out, e * NB + b, lo - 3);
}

// Grid 512: bid<128 -> merged heavy (e0+e1, b=bid); else e = 2+((bid-128)>>7), b=(bid-128)&127.
// All blocks of batch b have bid === b (mod 8) -> same XCD (shared L2 dedups plane reads).
__global__ __launch_bounds__(256, 4) void part_att_kernel(
    const float* __restrict__ x, float* __restrict__ out)
{
    __shared__ float2 u01[212];          // heavy: float2 weights; light: uses lu below
    __shared__ float  lu[212];
    __shared__ float  part[8][212];      // heavy: [0..3]=chain0, [4..7]=chain1
    __shared__ float  rv[256];
    __shared__ int    rix[256];

    const int bid = blockIdx.x;
    if (bid < 128) {
        const int b = bid;
        const float* xb = x + (size_t)b * ((size_t)NTOK * NTOK);
        chain_heavy(xb, out, b, u01, (float (*)[212])&part[0][0],
                    (float (*)[212])&part[4][0], rv, rix);
    } else {
        const int r = bid - 128;
        const int e = 2 + (r >> 7);
        const int b = r & 127;
        const int lo = (e == 2) ? 5 : (e == 3) ? 54 : 103;
        const float* xb = x + (size_t)b * ((size_t)NTOK * NTOK);
        chain_light(xb, out, e, b, lo, lu, part, rv, rix);
    }
}

extern "C" void kernel_launch(void* const* d_in, const int* in_sizes, int n_in,
                              void* d_out, int out_size, void* d_ws, size_t ws_size,
                              hipStream_t stream) {
    (void)in_sizes; (void)n_in; (void)d_ws; (void)ws_size; (void)out_size;
    const float* x = (const float*)d_in[0];
    float* out = (float*)d_out;
    part_att_kernel<<<dim3(512), dim3(256), 0, stream>>>(x, out);
}

// Round 10
// 75.194 us; speedup vs baseline: 1.0354x; 1.0354x over previous
//
#include <hip/hip_runtime.h>

#define NB 128
#define NTOK 201

// Publish LDS writes across a barrier WITHOUT draining vmcnt.
__device__ __forceinline__ void lds_barrier() {
    asm volatile("s_waitcnt lgkmcnt(0)" ::: "memory");
    __builtin_amdgcn_s_barrier();
}

__device__ __forceinline__ void argmax_write(
    float* rv, int* rix, float v, int idx, float* __restrict__ out, int slot, int base)
{
    const int tid = threadIdx.x;
    rv[tid] = v; rix[tid] = idx;
    __syncthreads();
    for (int s = 128; s > 0; s >>= 1) {
        if (tid < s) {
            const float v2 = rv[tid + s]; const int i2 = rix[tid + s];
            if (v2 > rv[tid] || (v2 == rv[tid] && i2 < rix[tid])) {
                rv[tid] = v2; rix[tid] = i2;
            }
        }
        __syncthreads();
    }
    if (tid == 0) {
        out[slot]       = rv[0];
        out[640 + slot] = (float)(base + rix[0]);
    }
}

// ---------- heavy chain: e in {0,1}, lo=5, M=197 ----------
// 4 row-classes (w = wave; rows xr = 4+w+4k, k=0..49) x 50 float4 col-groups.
// p = xcol - 2, valid [3,199). part layout TRANSPOSED: part[q][j][g] (stride-1
// reduce reads). Weights per wave in uw[w][k] (k=0..49), e-weight at [w][50].
__device__ __forceinline__ void chain_heavy(
    const float* __restrict__ xb, float* __restrict__ out,
    const int e, const int b,
    float* partbuf, float* uwb, float* rv, int* rix)
{
    const int tid = threadIdx.x;
    const int g   = tid & 63;
    const int w   = tid >> 6;
    const size_t plane = (size_t)NTOK * NTOK;

    const int t_w  = (4 - ((b + 2 + w) & 3)) & 3;   // p-offset of this class
    const int col0 = t_w + 2 + 4 * g;               // aligned xcol of lane's float4

    // init weights from layer-11 row e (wave-local, no barrier needed)
    const float* L11 = xb + (size_t)(11 * NB) * plane + (size_t)e * NTOK;
    if (g < 50) {
        const int p = 2 + w + 4 * g;
        uwb[w * 56 + g] = (p >= 3 && p < 199) ? L11[p + 2] : 0.f;
    } else if (g == 50) {
        uwb[w * 56 + 50] = L11[e];
    }

    int pb = 0;
    const float* A = xb + (size_t)(10 * NB) * plane;
    for (int l = 10; l >= 0; --l) {
        if (l < 10) {   // wave-local reduce of part[pb^1] -> uw[w]
            const float* pprev = partbuf + (pb ^ 1) * 896;
            if (g < 50) {
                const int p = 2 + w + 4 * g;
                float s = 0.f;
                if (p >= 3 && p < 199) {
                    #pragma unroll
                    for (int q = 0; q < 4; ++q) {
                        const int tq = (4 - ((b + 2 + q) & 3)) & 3;
                        const int d  = p - tq;
                        s += pprev[q * 224 + (d & 3) * 56 + (d >> 2)];
                    }
                }
                uwb[w * 56 + g] = s;
            } else if (g == 50) {
                float s = 0.f;
                #pragma unroll
                for (int q = 0; q < 4; ++q) s += pprev[q * 224 + 50];
                uwb[w * 56 + 50] = s;
            }
        }
        float* pcur = partbuf + pb * 896;
        if (g < 50) {
            float4 acc = make_float4(0.f, 0.f, 0.f, 0.f);
            if (w == e) {   // head row e (class w==e is alignment-matched)
                const float hw = uwb[w * 56 + 50];
                const float4 h = *(const float4*)(A + (size_t)e * NTOK + col0);
                acc.x = hw * h.x; acc.y = hw * h.y; acc.z = hw * h.z; acc.w = hw * h.w;
            }
            const float* rp = A + (size_t)(4 + w) * NTOK + col0;
            #pragma unroll
            for (int k = 0; k < 49; ++k) {
                const float wt = uwb[w * 56 + k];
                const float4 a = *(const float4*)(rp + (size_t)(4 * NTOK) * k);
                acc.x += wt * a.x; acc.y += wt * a.y; acc.z += wt * a.z; acc.w += wt * a.w;
            }
            {   // k=49: row 200+w; clamp in-class for w>=1 (weight there is 0)
                const float wt = uwb[w * 56 + 49];
                const float4 a = *(const float4*)(rp + (size_t)(4 * NTOK) * 49
                                                  - (w ? (size_t)(4 * NTOK) : 0));
                acc.x += wt * a.x; acc.y += wt * a.y; acc.z += wt * a.z; acc.w += wt * a.w;
            }
            float* pw = pcur + w * 224 + g;     // transposed store [w][j][g]
            pw[0] = acc.x; pw[56] = acc.y; pw[112] = acc.z; pw[168] = acc.w;
        } else if (g == 50) {                    // the e-column (att col 0)
            float s = 0.f;
            if (w == e) s = uwb[w * 56 + 50] * A[(size_t)e * NTOK + e];
            const float* ep = A + (size_t)(4 + w) * NTOK + e;
            #pragma unroll
            for (int k = 0; k < 49; ++k) s += uwb[w * 56 + k] * ep[(size_t)(4 * NTOK) * k];
            s += uwb[w * 56 + 49] * ep[(size_t)(4 * NTOK) * 49 - (w ? (size_t)(4 * NTOK) : 0)];
            pcur[w * 224 + 50] = s;
        }
        lds_barrier();      // the ONLY barrier per layer
        pb ^= 1;
        A -= (size_t)NB * plane;
    }

    // final u from part[pb^1]; argmax over p in [3,199); ref idx = p + 2
    const float* pfin = partbuf + (pb ^ 1) * 896;
    float v = -INFINITY; int idx = 0x7fffffff;
    if (tid >= 3 && tid < 199) {
        float s = 0.f;
        #pragma unroll
        for (int q = 0; q < 4; ++q) {
            const int tq = (4 - ((b + 2 + q) & 3)) & 3;
            const int d  = tid - tq;
            s += pfin[q * 224 + (d & 3) * 56 + (d >> 2)];
        }
        v = s; idx = tid;
    }
    argmax_write(rv, rix, v, idx, out, e * NB + b, 2);
}

// ---------- light chain: e in {2,3,4}, M=99 ----------
// 8 row-classes (rc = tid>>5; rows xr = lo-1+rc+8k, k=0..12) x 26 float4 groups.
// p = xcol-(lo-3), valid [3,101). Wave w owns classes 2w,2w+1; weights at
// uw[w][k] / uw[w][16+k]; e-weight at uw[w][30]. part[q][j][g], q<8, g<28.
__device__ __forceinline__ void chain_light(
    const float* __restrict__ xb, float* __restrict__ out,
    const int e, const int b, const int lo,
    float* partbuf, float* uwb, float* rv, int* rix)
{
    const int tid  = threadIdx.x;
    const int g5   = tid & 31;
    const int rc   = tid >> 5;            // 0..7
    const int w    = tid >> 6;            // 0..3
    const int kh   = (tid >> 5) & 1;      // rc = 2w + kh
    const int lane = tid & 63;
    const size_t plane = (size_t)NTOK * NTOK;

    const int ab    = b + 2 * lo - 4;                 // alignment base
    const int t_rc  = (4 - ((ab + rc) & 3)) & 3;
    const int col0  = t_rc + (lo - 3) + 4 * g5;
    const int rc_h  = (e - lo + 1) & 3;               // head-aligned class (=2 here)
    const int wbase = w * 56 + kh * 16;

    const float* L11 = xb + (size_t)(11 * NB) * plane + (size_t)e * NTOK;
    if (lane < 13) {
        const int p = 2 + 2 * w + 8 * lane;
        uwb[w * 56 + lane] = (p >= 3 && p < 101) ? L11[lo - 3 + p] : 0.f;
    } else if (lane >= 16 && lane < 29) {
        const int p = 3 + 2 * w + 8 * (lane - 16);
        uwb[w * 56 + lane] = (p >= 3 && p < 101) ? L11[lo - 3 + p] : 0.f;
    } else if (lane == 30) {
        uwb[w * 56 + 30] = L11[e];
    }

    int pb = 0;
    const float* A = xb + (size_t)(10 * NB) * plane;
    for (int l = 10; l >= 0; --l) {
        if (l < 10) {   // wave-local reduce -> this wave's 26 weights + EW
            const float* pprev = partbuf + (pb ^ 1) * 896;
            if (lane < 13 || (lane >= 16 && lane < 29)) {
                const int p = (lane < 13) ? (2 + 2 * w + 8 * lane)
                                          : (3 + 2 * w + 8 * (lane - 16));
                float s = 0.f;
                if (p >= 3 && p < 101) {
                    #pragma unroll
                    for (int q = 0; q < 8; ++q) {
                        const int tq = (4 - ((ab + q) & 3)) & 3;
                        const int d  = p - tq;
                        s += pprev[q * 112 + (d & 3) * 28 + (d >> 2)];
                    }
                }
                uwb[w * 56 + lane] = s;
            } else if (lane == 30) {
                float s = 0.f;
                #pragma unroll
                for (int q = 0; q < 8; ++q) s += pprev[q * 112 + 26];
                uwb[w * 56 + 30] = s;
            }
        }
        float* pcur = partbuf + pb * 896;
        if (g5 < 26) {
            float4 acc = make_float4(0.f, 0.f, 0.f, 0.f);
            if (rc == rc_h) {   // head row e (alignment-matched class)
                const float hw = uwb[w * 56 + 30];
                const float4 h = *(const float4*)(A + (size_t)e * NTOK + col0);
                acc.x = hw * h.x; acc.y = hw * h.y; acc.z = hw * h.z; acc.w = hw * h.w;
            }
            const float* rp = A + (size_t)(lo - 1 + rc) * NTOK + col0;
            #pragma unroll
            for (int k = 0; k < 12; ++k) {
                const float wt = uwb[wbase + k];
                const float4 a = *(const float4*)(rp + (size_t)(8 * NTOK) * k);
                acc.x += wt * a.x; acc.y += wt * a.y; acc.z += wt * a.z; acc.w += wt * a.w;
            }
            {   // k=12: slot 98+rc; clamp classes rc>=3 (zero weight)
                const float wt = uwb[wbase + 12];
                const float4 a = *(const float4*)(rp + (size_t)(8 * NTOK) * 12
                                                  - ((rc >= 3) ? (size_t)(8 * NTOK) : 0));
                acc.x += wt * a.x; acc.y += wt * a.y; acc.z += wt * a.z; acc.w += wt * a.w;
            }
            float* pw = pcur + rc * 112 + g5;
            pw[0] = acc.x; pw[28] = acc.y; pw[56] = acc.z; pw[84] = acc.w;
        } else if (g5 == 26) {               // e-column
            float s = 0.f;
            if (rc == 0) s = uwb[w * 56 + 30] * A[(size_t)e * NTOK + e];
            const float* ep = A + (size_t)(lo - 1 + rc) * NTOK + e;
            #pragma unroll
            for (int k = 0; k < 12; ++k) s += uwb[wbase + k] * ep[(size_t)(8 * NTOK) * k];
            s += uwb[wbase + 12] * ep[(size_t)(8 * NTOK) * 12 - ((rc >= 3) ? (size_t)(8 * NTOK) : 0)];
            pcur[rc * 112 + 26] = s;
        }
        lds_barrier();
        pb ^= 1;
        A -= (size_t)NB * plane;
    }

    const float* pfin = partbuf + (pb ^ 1) * 896;
    float v = -INFINITY; int idx = 0x7fffffff;
    if (tid >= 3 && tid < 101) {
        float s = 0.f;
        #pragma unroll
        for (int q = 0; q < 8; ++q) {
            const int tq = (4 - ((ab + q) & 3)) & 3;
            const int d  = tid - tq;
            s += pfin[q * 112 + (d & 3) * 28 + (d >> 2)];
        }
        v = s; idx = tid;
    }
    argmax_write(rv, rix, v, idx, out, e * NB + b, lo - 3);
}

// bid = 128*e + b => bid%8 = b%8: all 5 chains of a batch on the SAME XCD
// (its L2 dedups the overlapping window reads — light windows are subsets of
// the heavy window). 640 independent 4-wave blocks, ~2.5/CU interleaving.
__global__ __launch_bounds__(256, 4) void part_att_kernel(
    const float* __restrict__ x, float* __restrict__ out)
{
    __shared__ float partbuf[2 * 896];   // [pb][cls][j][g] transposed partials
    __shared__ float uwb[224];           // per-wave weight slices
    __shared__ float rv[256];
    __shared__ int   rix[256];

    const int bid = blockIdx.x;
    const int e   = bid >> 7;
    const int b   = bid & 127;
    const float* xb = x + (size_t)b * ((size_t)NTOK * NTOK);

    if (e < 2) {
        chain_heavy(xb, out, e, b, partbuf, uwb, rv, rix);
    } else {
        const int lo = (e == 2) ? 5 : (e == 3) ? 54 : 103;
        chain_light(xb, out, e, b, lo, partbuf, uwb, rv, rix);
    }
}

extern "C" void kernel_launch(void* const* d_in, const int* in_sizes, int n_in,
                              void* d_out, int out_size, void* d_ws, size_t ws_size,
                              hipStream_t stream) {
    (void)in_sizes; (void)n_in; (void)d_ws; (void)ws_size; (void)out_size;
    const float* x = (const float*)d_in[0];
    float* out = (float*)d_out;
    part_att_kernel<<<dim3(640), dim3(256), 0, stream>>>(x, out);
}